// Round 2
// baseline (203.107 us; speedup 1.0000x reference)
//
#include <hip/hip_runtime.h>

#define NPOS 8192
#define NCH  16
#define CHUNK (NPOS / NCH)   // 512
#define L2E 1.4426950408889634f

#if __has_builtin(__builtin_amdgcn_exp2f)
#define EXP2F(x) __builtin_amdgcn_exp2f(x)
#else
#define EXP2F(x) __expf((x) * 0.69314718055994531f)
#endif

// workspace layout (float offsets)
#define OFF_PART  0u          // 2*NCH*6*8192 = 1572864 floats
#define OFF_XA    1572864u    // 8192*4, flat row-major (4,8192)
#define OFF_SA    1605632u
#define OFF_MX2   1638400u    // flat (8192,4) == flat (4,8192) of Mx
#define OFF_MS2   1671168u

// ---------------------------------------------------------------- attn partials
// grid (32 j-blocks, NCH i-chunks, 2 branches), 256 threads.
// Each block recomputes Xe/Se for its i-tile and j-columns from X/S/W1.
// Chunk-local Cauchy-Schwarz shift: Mj_c = R_c * |xe_j| (log2 domain).
__global__ __launch_bounds__(256) void k_attn(
    const float* __restrict__ X, const float* __restrict__ S,
    const float* __restrict__ W1x, const float* __restrict__ W1s,
    float* __restrict__ ws)
{
    const int branch = blockIdx.z;
    const float* src = branch ? X : S;          // Xe = W1x@S, Se = W1s@X
    const float* W1  = branch ? W1s : W1x;
    float w[16];
#pragma unroll
    for (int i = 0; i < 16; ++i) w[i] = W1[i];

    __shared__ float4 tile[CHUNK];
    __shared__ float red[4];
    const int tid = threadIdx.x;
    const int i0 = blockIdx.y * CHUNK;

    float mloc = 0.f;
#pragma unroll
    for (int u0 = 0; u0 < CHUNK; u0 += 256) {
        int u = u0 + tid, i = i0 + u;
        float a0 = src[0*NPOS+i], a1 = src[1*NPOS+i];
        float a2 = src[2*NPOS+i], a3 = src[3*NPOS+i];
        float e0 = fmaf(w[ 0],a0,fmaf(w[ 1],a1,fmaf(w[ 2],a2,w[ 3]*a3)));
        float e1 = fmaf(w[ 4],a0,fmaf(w[ 5],a1,fmaf(w[ 6],a2,w[ 7]*a3)));
        float e2 = fmaf(w[ 8],a0,fmaf(w[ 9],a1,fmaf(w[10],a2,w[11]*a3)));
        float e3 = fmaf(w[12],a0,fmaf(w[13],a1,fmaf(w[14],a2,w[15]*a3)));
        tile[u] = make_float4(e0, e1, e2, e3);
        mloc = fmaxf(mloc, fmaf(e0,e0,fmaf(e1,e1,fmaf(e2,e2,e3*e3))));
    }
    // max tile-norm^2 -> R_c
    for (int off = 32; off; off >>= 1) mloc = fmaxf(mloc, __shfl_down(mloc, off));
    if ((tid & 63) == 0) red[tid >> 6] = mloc;
    __syncthreads();                     // also publishes tile[]
    float R = sqrtf(fmaxf(fmaxf(red[0], red[1]), fmaxf(red[2], red[3])));

    // this thread's j column
    int j = blockIdx.x * 256 + tid;
    float b0 = src[0*NPOS+j], b1 = src[1*NPOS+j];
    float b2 = src[2*NPOS+j], b3 = src[3*NPOS+j];
    float q0 = fmaf(w[ 0],b0,fmaf(w[ 1],b1,fmaf(w[ 2],b2,w[ 3]*b3)));
    float q1 = fmaf(w[ 4],b0,fmaf(w[ 5],b1,fmaf(w[ 6],b2,w[ 7]*b3)));
    float q2 = fmaf(w[ 8],b0,fmaf(w[ 9],b1,fmaf(w[10],b2,w[11]*b3)));
    float q3 = fmaf(w[12],b0,fmaf(w[13],b1,fmaf(w[14],b2,w[15]*b3)));
    float nj = sqrtf(fmaf(q0,q0,fmaf(q1,q1,fmaf(q2,q2,q3*q3))));
    float Mj = R * nj * L2E;             // log2-domain shift, >= max_i s'_ij
    float negM = -Mj;
    float x0 = q0*L2E, x1 = q1*L2E, x2 = q2*L2E, x3 = q3*L2E;

    float den = 0.f, n0 = 0.f, n1 = 0.f, n2 = 0.f, n3 = 0.f;
#pragma unroll 4
    for (int u = 0; u < CHUNK; ++u) {
        float4 xi = tile[u];
        float s = fmaf(x0,xi.x, fmaf(x1,xi.y, fmaf(x2,xi.z, fmaf(x3,xi.w, negM))));
        float p = EXP2F(s);
        den += p;
        n0 = fmaf(p, xi.x, n0);
        n1 = fmaf(p, xi.y, n1);
        n2 = fmaf(p, xi.z, n2);
        n3 = fmaf(p, xi.w, n3);
    }
    float* part = ws + OFF_PART + (size_t)(branch * NCH + blockIdx.y) * 6 * NPOS;
    part[0*NPOS + j] = n0;
    part[1*NPOS + j] = n1;
    part[2*NPOS + j] = n2;
    part[3*NPOS + j] = n3;
    part[4*NPOS + j] = den;
    part[5*NPOS + j] = Mj;
}

// ---------------------------------------------------------------- finalize Xa/Sa
__global__ __launch_bounds__(256) void k_fin(float* __restrict__ ws)
{
    int branch = blockIdx.y;
    int j = blockIdx.x * 256 + threadIdx.x;
    const float* base = ws + OFF_PART + (size_t)branch * NCH * 6 * NPOS + j;
    float M = 0.f;
#pragma unroll
    for (int c = 0; c < NCH; ++c) M = fmaxf(M, base[(size_t)(c*6+5) * NPOS]);
    float n0=0.f, n1=0.f, n2=0.f, n3=0.f, den=0.f;
#pragma unroll
    for (int c = 0; c < NCH; ++c) {
        const float* p = base + (size_t)c * 6 * NPOS;
        float wgt = EXP2F(p[5*NPOS] - M);
        n0 = fmaf(p[0*NPOS], wgt, n0);
        n1 = fmaf(p[1*NPOS], wgt, n1);
        n2 = fmaf(p[2*NPOS], wgt, n2);
        n3 = fmaf(p[3*NPOS], wgt, n3);
        den = fmaf(p[4*NPOS], wgt, den);
    }
    float inv = 1.0f / den;
    float* out = ws + (branch ? OFF_SA : OFF_XA);
    out[0*NPOS + j] = n0 * inv;
    out[1*NPOS + j] = n1 * inv;
    out[2*NPOS + j] = n2 * inv;
    out[3*NPOS + j] = n3 * inv;
}

// ---------------------------------------------------------------- M = W2 @ [Xa2|Sa2]
// 4 rows of W2 per block; lanes stride k in float4 units; 32 accumulators.
#define ACC4(r, wv, q0, q1, q2, q3, comp, cc)                 \
    acc[r][cc] = fmaf(wv.x, q0.comp, acc[r][cc]);             \
    acc[r][cc] = fmaf(wv.y, q1.comp, acc[r][cc]);             \
    acc[r][cc] = fmaf(wv.z, q2.comp, acc[r][cc]);             \
    acc[r][cc] = fmaf(wv.w, q3.comp, acc[r][cc]);

__global__ __launch_bounds__(256) void k_gemv(
    const float* __restrict__ W2, float* __restrict__ ws)
{
    const float* xa = ws + OFF_XA;
    const float* sa = ws + OFF_SA;
    int r0 = blockIdx.x * 4;
    int tid = threadIdx.x;

    float acc[4][8];
#pragma unroll
    for (int r = 0; r < 4; ++r)
#pragma unroll
        for (int c = 0; c < 8; ++c) acc[r][c] = 0.f;

    for (int it = 0; it < 8; ++it) {
        int k4 = it * 256 + tid;                 // 16-float group along k
        const float4* xp = (const float4*)(xa + (size_t)k4 * 16);
        const float4* sp = (const float4*)(sa + (size_t)k4 * 16);
        float4 a0 = xp[0], a1 = xp[1], a2 = xp[2], a3 = xp[3];
        float4 b0 = sp[0], b1 = sp[1], b2 = sp[2], b3 = sp[3];
#pragma unroll
        for (int r = 0; r < 4; ++r) {
            float4 wv = *(const float4*)(W2 + (size_t)(r0 + r) * NPOS + (size_t)k4 * 4);
            ACC4(r, wv, a0, a1, a2, a3, x, 0)
            ACC4(r, wv, a0, a1, a2, a3, y, 1)
            ACC4(r, wv, a0, a1, a2, a3, z, 2)
            ACC4(r, wv, a0, a1, a2, a3, w, 3)
            ACC4(r, wv, b0, b1, b2, b3, x, 4)
            ACC4(r, wv, b0, b1, b2, b3, y, 5)
            ACC4(r, wv, b0, b1, b2, b3, z, 6)
            ACC4(r, wv, b0, b1, b2, b3, w, 7)
        }
    }

    __shared__ float sred[4 * 32];
    int wave = tid >> 6, lane = tid & 63;
#pragma unroll
    for (int r = 0; r < 4; ++r)
#pragma unroll
        for (int c = 0; c < 8; ++c) {
            float v = acc[r][c];
            for (int off = 32; off; off >>= 1) v += __shfl_down(v, off);
            if (lane == 0) sred[wave * 32 + r * 8 + c] = v;
        }
    __syncthreads();
    if (tid < 32) {
        float v = sred[tid] + sred[32 + tid] + sred[64 + tid] + sred[96 + tid];
        int r = tid >> 3, c = tid & 7;
        float* dst = ws + ((c < 4) ? OFF_MX2 : OFF_MS2);
        dst[(size_t)(r0 + r) * 4 + (c & 3)] = v;
    }
}

// ---------------------------------------------------------------- epilogue + 3x1 conv
__global__ __launch_bounds__(256) void k_conv(
    const float* __restrict__ X, const float* __restrict__ S,
    const float* __restrict__ cwx, const float* __restrict__ cbx,
    const float* __restrict__ cws, const float* __restrict__ cbs,
    const float* __restrict__ ws, float* __restrict__ out)
{
    int branch = blockIdx.y;
    int k0 = blockIdx.x * 256;
    const float* M2 = ws + (branch ? OFF_MS2 : OFF_MX2);
    const float* cw = branch ? cws : cwx;
    const float* cb = branch ? cbs : cbx;

    __shared__ float h[8][264];     // channels x (k0-1 .. k0+256)
    __shared__ float wg[192];       // w[co][ci][kh] (kw=1 only; W=1 image)
    __shared__ float bg[8];

    int tid = threadIdx.x;
    if (tid < 192) {
        int co = tid / 24, rem = tid % 24, ci = rem / 3, kh = rem % 3;
        wg[tid] = cw[co * 72 + ci * 9 + kh * 3 + 1];
    }
    if (tid < 8) bg[tid] = cb[tid];

    for (int idx = tid; idx < 8 * 258; idx += 256) {
        int ch = idx / 258, kk = idx % 258;
        int k = k0 - 1 + kk;
        float v = 0.f;
        if (k >= 0 && k < NPOS) {
            int l = ch & 3;
            if (branch == 0) {
                float xv = X[l * NPOS + k];
                v = (ch < 4) ? M2[l * NPOS + k] * xv : xv;
            } else {
                v = (ch < 4) ? M2[l * NPOS + k] * X[l * NPOS + k] : S[l * NPOS + k];
                v += sinf((float)k);      // sinusoid table with d_hid=B=1 -> sin(pos)
            }
        }
        h[ch][kk] = v;
    }
    __syncthreads();

    int k = k0 + tid;
    int kk = tid + 1;
#pragma unroll
    for (int co = 0; co < 8; ++co) {
        float a = bg[co];
#pragma unroll
        for (int ci = 0; ci < 8; ++ci) {
            a = fmaf(wg[co * 24 + ci * 3 + 0], h[ci][kk - 1], a);
            a = fmaf(wg[co * 24 + ci * 3 + 1], h[ci][kk    ], a);
            a = fmaf(wg[co * 24 + ci * 3 + 2], h[ci][kk + 1], a);
        }
        out[(size_t)(branch * 8 + co) * NPOS + k] = a;
    }
}

// ----------------------------------------------------------------
extern "C" void kernel_launch(void* const* d_in, const int* in_sizes, int n_in,
                              void* d_out, int out_size, void* d_ws, size_t ws_size,
                              hipStream_t stream)
{
    const float* X   = (const float*)d_in[0];
    const float* S   = (const float*)d_in[1];
    const float* W1x = (const float*)d_in[2];
    const float* W1s = (const float*)d_in[3];
    const float* W2  = (const float*)d_in[4];
    const float* cwx = (const float*)d_in[5];
    const float* cbx = (const float*)d_in[6];
    const float* cws = (const float*)d_in[7];
    const float* cbs = (const float*)d_in[8];
    float* out = (float*)d_out;
    float* ws  = (float*)d_ws;

    k_attn<<<dim3(NPOS / 256, NCH, 2), 256, 0, stream>>>(X, S, W1x, W1s, ws);
    k_fin<<<dim3(NPOS / 256, 2), 256, 0, stream>>>(ws);
    k_gemv<<<dim3(NPOS / 4), 256, 0, stream>>>(W2, ws);
    k_conv<<<dim3(NPOS / 256, 2), 256, 0, stream>>>(X, S, cwx, cbx, cws, cbs, ws, out);
}

// Round 3
// 107.919 us; speedup vs baseline: 1.8820x; 1.8820x over previous
//
#include <hip/hip_runtime.h>

#define NPOS 8192
#define NCH  16
#define CHUNK (NPOS / NCH)   // 512
#define L2E 1.4426950408889634f

#if __has_builtin(__builtin_amdgcn_exp2f)
#define EXP2F(x) __builtin_amdgcn_exp2f(x)
#else
#define EXP2F(x) __expf((x) * 0.69314718055994531f)
#endif

// workspace layout (float offsets)
#define OFF_PART  0u          // 2*NCH*6*8192 = 1572864 floats
#define OFF_XA    1572864u    // 8192*4, flat row-major (4,8192)
#define OFF_SA    1605632u
#define OFF_MX2A  1638400u    // partial W2@Xa2, k-half A   (flat (8192,4))
#define OFF_MS2A  1671168u
#define OFF_MX2B  1703936u    // k-half B
#define OFF_MS2B  1736704u

// ---------------------------------------------------------------- attn partials
__global__ __launch_bounds__(256) void k_attn(
    const float* __restrict__ X, const float* __restrict__ S,
    const float* __restrict__ W1x, const float* __restrict__ W1s,
    float* __restrict__ ws)
{
    const int branch = blockIdx.z;
    const float* src = branch ? X : S;          // Xe = W1x@S, Se = W1s@X
    const float* W1  = branch ? W1s : W1x;
    float w[16];
#pragma unroll
    for (int i = 0; i < 16; ++i) w[i] = W1[i];

    __shared__ float4 tile[CHUNK];
    __shared__ float red[4];
    const int tid = threadIdx.x;
    const int i0 = blockIdx.y * CHUNK;

    float mloc = 0.f;
#pragma unroll
    for (int u0 = 0; u0 < CHUNK; u0 += 256) {
        int u = u0 + tid, i = i0 + u;
        float a0 = src[0*NPOS+i], a1 = src[1*NPOS+i];
        float a2 = src[2*NPOS+i], a3 = src[3*NPOS+i];
        float e0 = fmaf(w[ 0],a0,fmaf(w[ 1],a1,fmaf(w[ 2],a2,w[ 3]*a3)));
        float e1 = fmaf(w[ 4],a0,fmaf(w[ 5],a1,fmaf(w[ 6],a2,w[ 7]*a3)));
        float e2 = fmaf(w[ 8],a0,fmaf(w[ 9],a1,fmaf(w[10],a2,w[11]*a3)));
        float e3 = fmaf(w[12],a0,fmaf(w[13],a1,fmaf(w[14],a2,w[15]*a3)));
        tile[u] = make_float4(e0, e1, e2, e3);
        mloc = fmaxf(mloc, fmaf(e0,e0,fmaf(e1,e1,fmaf(e2,e2,e3*e3))));
    }
    for (int off = 32; off; off >>= 1) mloc = fmaxf(mloc, __shfl_down(mloc, off));
    if ((tid & 63) == 0) red[tid >> 6] = mloc;
    __syncthreads();
    float R = sqrtf(fmaxf(fmaxf(red[0], red[1]), fmaxf(red[2], red[3])));

    int j = blockIdx.x * 256 + tid;
    float b0 = src[0*NPOS+j], b1 = src[1*NPOS+j];
    float b2 = src[2*NPOS+j], b3 = src[3*NPOS+j];
    float q0 = fmaf(w[ 0],b0,fmaf(w[ 1],b1,fmaf(w[ 2],b2,w[ 3]*b3)));
    float q1 = fmaf(w[ 4],b0,fmaf(w[ 5],b1,fmaf(w[ 6],b2,w[ 7]*b3)));
    float q2 = fmaf(w[ 8],b0,fmaf(w[ 9],b1,fmaf(w[10],b2,w[11]*b3)));
    float q3 = fmaf(w[12],b0,fmaf(w[13],b1,fmaf(w[14],b2,w[15]*b3)));
    float nj = sqrtf(fmaf(q0,q0,fmaf(q1,q1,fmaf(q2,q2,q3*q3))));
    float Mj = R * nj * L2E;
    float negM = -Mj;
    float x0 = q0*L2E, x1 = q1*L2E, x2 = q2*L2E, x3 = q3*L2E;

    float den = 0.f, n0 = 0.f, n1 = 0.f, n2 = 0.f, n3 = 0.f;
#pragma unroll 4
    for (int u = 0; u < CHUNK; ++u) {
        float4 xi = tile[u];
        float s = fmaf(x0,xi.x, fmaf(x1,xi.y, fmaf(x2,xi.z, fmaf(x3,xi.w, negM))));
        float p = EXP2F(s);
        den += p;
        n0 = fmaf(p, xi.x, n0);
        n1 = fmaf(p, xi.y, n1);
        n2 = fmaf(p, xi.z, n2);
        n3 = fmaf(p, xi.w, n3);
    }
    float* part = ws + OFF_PART + (size_t)(branch * NCH + blockIdx.y) * 6 * NPOS;
    part[0*NPOS + j] = n0;
    part[1*NPOS + j] = n1;
    part[2*NPOS + j] = n2;
    part[3*NPOS + j] = n3;
    part[4*NPOS + j] = den;
    part[5*NPOS + j] = Mj;
}

// ---------------------------------------------------------------- finalize Xa/Sa
__global__ __launch_bounds__(256) void k_fin(float* __restrict__ ws)
{
    int branch = blockIdx.y;
    int j = blockIdx.x * 256 + threadIdx.x;
    const float* base = ws + OFF_PART + (size_t)branch * NCH * 6 * NPOS + j;
    float M = 0.f;
#pragma unroll
    for (int c = 0; c < NCH; ++c) M = fmaxf(M, base[(size_t)(c*6+5) * NPOS]);
    float n0=0.f, n1=0.f, n2=0.f, n3=0.f, den=0.f;
#pragma unroll
    for (int c = 0; c < NCH; ++c) {
        const float* p = base + (size_t)c * 6 * NPOS;
        float wgt = EXP2F(p[5*NPOS] - M);
        n0 = fmaf(p[0*NPOS], wgt, n0);
        n1 = fmaf(p[1*NPOS], wgt, n1);
        n2 = fmaf(p[2*NPOS], wgt, n2);
        n3 = fmaf(p[3*NPOS], wgt, n3);
        den = fmaf(p[4*NPOS], wgt, den);
    }
    float inv = 1.0f / den;
    float* out = ws + (branch ? OFF_SA : OFF_XA);
    out[0*NPOS + j] = n0 * inv;
    out[1*NPOS + j] = n1 * inv;
    out[2*NPOS + j] = n2 * inv;
    out[3*NPOS + j] = n3 * inv;
}

// ---------------------------------------------------------------- M = W2 @ [Xa2|Sa2]
// grid (512 row-tiles, 2 k-halves). Block: 4 waves x 4 rows/thread = 16 rows.
// Per k-half: 4 phases of 1024 k. A (xa/sa) staged in LDS, XOR-swizzled.
__global__ __launch_bounds__(256, 4) void k_gemv(
    const float* __restrict__ W2, float* __restrict__ ws)
{
    __shared__ float4 lx[1024];
    __shared__ float4 lsb[1024];
    const int tid  = threadIdx.x;
    const int wave = tid >> 6, lane = tid & 63;
    const int half = blockIdx.y;
    const int r0   = blockIdx.x * 16 + wave * 4;
    const float4* xa4 = (const float4*)(ws + OFF_XA);   // f4 index == k
    const float4* sa4 = (const float4*)(ws + OFF_SA);
    const float*  wr  = W2 + (size_t)r0 * NPOS;

    float acc[4][8];
#pragma unroll
    for (int r = 0; r < 4; ++r)
#pragma unroll
        for (int c = 0; c < 8; ++c) acc[r][c] = 0.f;

    for (int ph = 0; ph < 4; ++ph) {
        const int kbase = half * 4096 + ph * 1024;
        if (ph) __syncthreads();
#pragma unroll
        for (int p = 0; p < 4; ++p) {
            int t  = p * 256 + tid;                  // f4 idx within chunk
            int sw = t ^ ((t >> 2) & 7);
            lx[sw]  = xa4[kbase + t];
            lsb[sw] = sa4[kbase + t];
        }
        __syncthreads();
#pragma unroll
        for (int s = 0; s < 4; ++s) {
            int q = s * 64 + lane;                   // k4-group within chunk
            float4 w0 = *(const float4*)(wr + 0*NPOS + kbase + q*4);
            float4 w1 = *(const float4*)(wr + 1*NPOS + kbase + q*4);
            float4 w2v= *(const float4*)(wr + 2*NPOS + kbase + q*4);
            float4 w3 = *(const float4*)(wr + 3*NPOS + kbase + q*4);
            int ib = (4*q) ^ (q & 7);
            float4 a[4], b[4];
#pragma unroll
            for (int m = 0; m < 4; ++m) { a[m] = lx[ib ^ m]; b[m] = lsb[ib ^ m]; }
#pragma unroll
            for (int m = 0; m < 4; ++m) {
                float c0 = (m==0)?w0.x:(m==1)?w0.y:(m==2)?w0.z:w0.w;
                float c1 = (m==0)?w1.x:(m==1)?w1.y:(m==2)?w1.z:w1.w;
                float c2 = (m==0)?w2v.x:(m==1)?w2v.y:(m==2)?w2v.z:w2v.w;
                float c3 = (m==0)?w3.x:(m==1)?w3.y:(m==2)?w3.z:w3.w;
                acc[0][0]=fmaf(c0,a[m].x,acc[0][0]); acc[0][1]=fmaf(c0,a[m].y,acc[0][1]);
                acc[0][2]=fmaf(c0,a[m].z,acc[0][2]); acc[0][3]=fmaf(c0,a[m].w,acc[0][3]);
                acc[0][4]=fmaf(c0,b[m].x,acc[0][4]); acc[0][5]=fmaf(c0,b[m].y,acc[0][5]);
                acc[0][6]=fmaf(c0,b[m].z,acc[0][6]); acc[0][7]=fmaf(c0,b[m].w,acc[0][7]);
                acc[1][0]=fmaf(c1,a[m].x,acc[1][0]); acc[1][1]=fmaf(c1,a[m].y,acc[1][1]);
                acc[1][2]=fmaf(c1,a[m].z,acc[1][2]); acc[1][3]=fmaf(c1,a[m].w,acc[1][3]);
                acc[1][4]=fmaf(c1,b[m].x,acc[1][4]); acc[1][5]=fmaf(c1,b[m].y,acc[1][5]);
                acc[1][6]=fmaf(c1,b[m].z,acc[1][6]); acc[1][7]=fmaf(c1,b[m].w,acc[1][7]);
                acc[2][0]=fmaf(c2,a[m].x,acc[2][0]); acc[2][1]=fmaf(c2,a[m].y,acc[2][1]);
                acc[2][2]=fmaf(c2,a[m].z,acc[2][2]); acc[2][3]=fmaf(c2,a[m].w,acc[2][3]);
                acc[2][4]=fmaf(c2,b[m].x,acc[2][4]); acc[2][5]=fmaf(c2,b[m].y,acc[2][5]);
                acc[2][6]=fmaf(c2,b[m].z,acc[2][6]); acc[2][7]=fmaf(c2,b[m].w,acc[2][7]);
                acc[3][0]=fmaf(c3,a[m].x,acc[3][0]); acc[3][1]=fmaf(c3,a[m].y,acc[3][1]);
                acc[3][2]=fmaf(c3,a[m].z,acc[3][2]); acc[3][3]=fmaf(c3,a[m].w,acc[3][3]);
                acc[3][4]=fmaf(c3,b[m].x,acc[3][4]); acc[3][5]=fmaf(c3,b[m].y,acc[3][5]);
                acc[3][6]=fmaf(c3,b[m].z,acc[3][6]); acc[3][7]=fmaf(c3,b[m].w,acc[3][7]);
            }
        }
    }

    // 64-lane reduce each acc, lane 0 writes
    float* mx = ws + (half ? OFF_MX2B : OFF_MX2A);
    float* msb= ws + (half ? OFF_MS2B : OFF_MS2A);
#pragma unroll
    for (int r = 0; r < 4; ++r)
#pragma unroll
        for (int c = 0; c < 8; ++c) {
            float v = acc[r][c];
            for (int off = 32; off; off >>= 1) v += __shfl_down(v, off);
            if (lane == 0) {
                float* dst = (c < 4) ? mx : msb;
                dst[(size_t)(r0 + r) * 4 + (c & 3)] = v;
            }
        }
}

// ---------------------------------------------------------------- epilogue + 3x1 conv
__global__ __launch_bounds__(256) void k_conv(
    const float* __restrict__ X, const float* __restrict__ S,
    const float* __restrict__ cwx, const float* __restrict__ cbx,
    const float* __restrict__ cws, const float* __restrict__ cbs,
    const float* __restrict__ ws, float* __restrict__ out)
{
    int branch = blockIdx.y;
    int k0 = blockIdx.x * 256;
    const float* M2a = ws + (branch ? OFF_MS2A : OFF_MX2A);
    const float* M2b = ws + (branch ? OFF_MS2B : OFF_MX2B);
    const float* cw = branch ? cws : cwx;
    const float* cb = branch ? cbs : cbx;

    __shared__ float h[8][264];
    __shared__ float wg[192];
    __shared__ float bg[8];

    int tid = threadIdx.x;
    if (tid < 192) {
        int co = tid / 24, rem = tid % 24, ci = rem / 3, kh = rem % 3;
        wg[tid] = cw[co * 72 + ci * 9 + kh * 3 + 1];
    }
    if (tid < 8) bg[tid] = cb[tid];

    for (int idx = tid; idx < 8 * 258; idx += 256) {
        int ch = idx / 258, kk = idx % 258;
        int k = k0 - 1 + kk;
        float v = 0.f;
        if (k >= 0 && k < NPOS) {
            int l = ch & 3;
            size_t fi = (size_t)l * NPOS + k;
            if (branch == 0) {
                float xv = X[fi];
                v = (ch < 4) ? (M2a[fi] + M2b[fi]) * xv : xv;
            } else {
                v = (ch < 4) ? (M2a[fi] + M2b[fi]) * X[fi] : S[fi];
                v += sinf((float)k);
            }
        }
        h[ch][kk] = v;
    }
    __syncthreads();

    int k = k0 + tid;
    int kk = tid + 1;
#pragma unroll
    for (int co = 0; co < 8; ++co) {
        float a = bg[co];
#pragma unroll
        for (int ci = 0; ci < 8; ++ci) {
            a = fmaf(wg[co * 24 + ci * 3 + 0], h[ci][kk - 1], a);
            a = fmaf(wg[co * 24 + ci * 3 + 1], h[ci][kk    ], a);
            a = fmaf(wg[co * 24 + ci * 3 + 2], h[ci][kk + 1], a);
        }
        out[(size_t)(branch * 8 + co) * NPOS + k] = a;
    }
}

// ----------------------------------------------------------------
extern "C" void kernel_launch(void* const* d_in, const int* in_sizes, int n_in,
                              void* d_out, int out_size, void* d_ws, size_t ws_size,
                              hipStream_t stream)
{
    const float* X   = (const float*)d_in[0];
    const float* S   = (const float*)d_in[1];
    const float* W1x = (const float*)d_in[2];
    const float* W1s = (const float*)d_in[3];
    const float* W2  = (const float*)d_in[4];
    const float* cwx = (const float*)d_in[5];
    const float* cbx = (const float*)d_in[6];
    const float* cws = (const float*)d_in[7];
    const float* cbs = (const float*)d_in[8];
    float* out = (float*)d_out;
    float* ws  = (float*)d_ws;

    k_attn<<<dim3(NPOS / 256, NCH, 2), 256, 0, stream>>>(X, S, W1x, W1s, ws);
    k_fin<<<dim3(NPOS / 256, 2), 256, 0, stream>>>(ws);
    k_gemv<<<dim3(NPOS / 16, 2), 256, 0, stream>>>(W2, ws);
    k_conv<<<dim3(NPOS / 256, 2), 256, 0, stream>>>(X, S, cwx, cbx, cws, cbs, ws, out);
}